// Round 10
// baseline (1080.980 us; speedup 1.0000x reference)
//
#include <hip/hip_runtime.h>
#include <hip/hip_fp16.h>

#define NFEAT_IN 21
#define NHID 16
#define NOUT 6
#define BSHIFT 7
#define BW (1 << BSHIFT)     // 128 nodes per bucket
#define NBMAX 2048           // supports n <= 262144
#define EPT 32
#define PB 256
#define CHUNK (PB * EPT)     // 8192 edges per partition block

__global__ void k_zero(int* __restrict__ p, int n) {
    int i = blockIdx.x * blockDim.x + threadIdx.x;
    if (i < n) p[i] = 0;
}

__global__ void k_hist(const int* __restrict__ dst, int* __restrict__ bcnt, int ne) {
    __shared__ int lcnt[NBMAX];
    for (int t = threadIdx.x; t < NBMAX; t += blockDim.x) lcnt[t] = 0;
    __syncthreads();
    int stride = gridDim.x * blockDim.x;
    for (int e = blockIdx.x * blockDim.x + threadIdx.x; e < ne; e += stride)
        atomicAdd(&lcnt[dst[e] >> BSHIFT], 1);
    __syncthreads();
    for (int t = threadIdx.x; t < NBMAX; t += blockDim.x)
        if (lcnt[t]) atomicAdd(&bcnt[t], lcnt[t]);
}

__global__ void k_scan(const int* __restrict__ bcnt, int* __restrict__ boff,
                       int* __restrict__ bcur) {
    __shared__ int s[1024];
    int t = threadIdx.x;
    int v0 = bcnt[2 * t], v1 = bcnt[2 * t + 1];
    int pair = v0 + v1;
    s[t] = pair;
    __syncthreads();
    for (int off = 1; off < 1024; off <<= 1) {
        int tv = (t >= off) ? s[t - off] : 0;
        __syncthreads();
        s[t] += tv;
        __syncthreads();
    }
    int ex = s[t] - pair;
    boff[2 * t] = ex;      bcur[2 * t] = ex;
    boff[2 * t + 1] = ex + v0;  bcur[2 * t + 1] = ex + v0;
}

__global__ void k_partition(const int* __restrict__ src, const int* __restrict__ dst,
                            int* __restrict__ bcur, unsigned int* __restrict__ bucketed,
                            int ne) {
    __shared__ unsigned int ebd[CHUNK];   // (bucket<<16)|dst_local
    __shared__ int lcnt[NBMAX];
    __shared__ int lbase[NBMAX];
    __shared__ int lcur[NBMAX];
    int t = threadIdx.x;
    long base = (long)blockIdx.x * CHUNK;
    for (int b = t; b < NBMAX; b += PB) lcnt[b] = 0;
    __syncthreads();
#pragma unroll
    for (int k = 0; k < EPT; k++) {
        int idx = t + k * PB;
        long e = base + idx;
        unsigned int v = 0xFFFF0000u;
        if (e < ne) {
            int d = dst[e];
            int b = d >> BSHIFT;
            v = ((unsigned int)b << 16) | (unsigned int)(d & (BW - 1));
            atomicAdd(&lcnt[b], 1);
        }
        ebd[idx] = v;
    }
    __syncthreads();
    for (int b = t; b < NBMAX; b += PB) {
        int c = lcnt[b];
        if (c > 0) lbase[b] = atomicAdd(&bcur[b], c);
        lcur[b] = 0;
    }
    __syncthreads();
#pragma unroll
    for (int k = 0; k < EPT; k++) {
        int idx = t + k * PB;
        unsigned int v = ebd[idx];
        unsigned int b = v >> 16;
        if (b == 0xFFFFu) continue;
        int r = atomicAdd(&lcur[b], 1);
        int s = src[base + idx];
        bucketed[lbase[b] + r] = ((unsigned int)s << BSHIFT) | (v & (BW - 1));
    }
}

__global__ void k_bucket_dinv(const unsigned int* __restrict__ bucketed,
                              const int* __restrict__ boff, const int* __restrict__ bcnt,
                              float* __restrict__ dinv, int n) {
    __shared__ int deg[BW];
    int b = blockIdx.x, t = threadIdx.x;
    if (t < BW) deg[t] = 0;
    __syncthreads();
    int s0 = boff[b], c = bcnt[b];
    for (int j = t; j < c; j += blockDim.x) atomicAdd(&deg[bucketed[s0 + j] & (BW - 1)], 1);
    __syncthreads();
    if (t < BW) {
        int node = (b << BSHIFT) + t;
        if (node < n) dinv[node] = rsqrtf((float)deg[t] + 1.0f);
    }
}

// dense1 writes TWO half-feature tables, 16B/node each (3.2MB: per-XCD-L2
// resident). hA = feats 0-7, hB = feats 8-15, both fp16 * dinv.
__global__ void k_dense1(const float* __restrict__ x, const float* __restrict__ W1,
                         const float* __restrict__ dinv, uint4* __restrict__ hA,
                         uint4* __restrict__ hB, int n) {
    __shared__ float sW[NFEAT_IN * NHID];
    for (int t = threadIdx.x; t < NFEAT_IN * NHID; t += blockDim.x) sW[t] = W1[t];
    __syncthreads();
    int i = blockIdx.x * blockDim.x + threadIdx.x;
    if (i >= n) return;
    float xi[NFEAT_IN];
#pragma unroll
    for (int k = 0; k < NFEAT_IN; k++) xi[k] = x[(size_t)i * NFEAT_IN + k];
    float di = dinv[i];
    float r[NHID];
#pragma unroll
    for (int j = 0; j < NHID; j++) {
        float acc = 0.f;
#pragma unroll
        for (int k = 0; k < NFEAT_IN; k++) acc += xi[k] * sW[k * NHID + j];
        r[j] = acc * di;
    }
    union { __half2 h[4]; uint4 u; } pa, pb;
#pragma unroll
    for (int q = 0; q < 4; q++) {
        pa.h[q] = __floats2half2_rn(r[2 * q], r[2 * q + 1]);
        pb.h[q] = __floats2half2_rn(r[8 + 2 * q], r[9 + 2 * q]);
    }
    hA[i] = pa.u;
    hB[i] = pb.u;
}

__device__ __forceinline__ void acc8(float* a, uint4 u) {
    unsigned int us[4] = {u.x, u.y, u.z, u.w};
#pragma unroll
    for (int q = 0; q < 4; q++) {
        float2 f = __half22float2(*(const __half2*)&us[q]);
        atomicAdd(a + 2 * q, f.x);
        atomicAdd(a + 2 * q + 1, f.y);
    }
}

// Pass A: aggregate feats 0-7 from the L2-resident 3.2MB hA table.
// Writes fp32 partial sums (incl. self) to aggA, 32B/node sequential.
__global__ __launch_bounds__(256, 4) void
k_agg1a(const unsigned int* __restrict__ bucketed, const int* __restrict__ boff,
        const int* __restrict__ bcnt, const uint4* __restrict__ hA,
        float* __restrict__ aggA, int n) {
    __shared__ float acc[BW * 9];
    int b = blockIdx.x, t = threadIdx.x;
    for (int k = t; k < BW * 9; k += 256) acc[k] = 0.f;
    __syncthreads();
    int s0 = boff[b], c = bcnt[b];
    for (int j = s0 + t, jend = s0 + c; j < jend; j += 256) {
        unsigned int p = __builtin_nontemporal_load(bucketed + j);
        uint4 u = hA[p >> BSHIFT];
        acc8(acc + (p & (BW - 1)) * 9, u);
    }
    __syncthreads();
    if (t >= BW) return;
    int node = (b << BSHIFT) + t;
    if (node >= n) return;
    uint4 sv = hA[node];
    unsigned int us[4] = {sv.x, sv.y, sv.z, sv.w};
    float* a = acc + t * 9;
    float4 o0, o1;
    float o[8];
#pragma unroll
    for (int q = 0; q < 4; q++) {
        float2 f = __half22float2(*(const __half2*)&us[q]);
        o[2 * q]     = a[2 * q] + f.x;
        o[2 * q + 1] = a[2 * q + 1] + f.y;
    }
    o0 = make_float4(o[0], o[1], o[2], o[3]);
    o1 = make_float4(o[4], o[5], o[6], o[7]);
    float4* op = (float4*)(aggA + (size_t)node * 8);
    op[0] = o0;
    op[1] = o1;
}

// Pass B: aggregate feats 8-15 from hB, combine with aggA, relu + dense2,
// write hs2h (16B/node fp16).
__global__ __launch_bounds__(256, 4) void
k_agg1b(const unsigned int* __restrict__ bucketed, const int* __restrict__ boff,
        const int* __restrict__ bcnt, const uint4* __restrict__ hB,
        const float* __restrict__ aggA, const float* __restrict__ b1,
        const float* __restrict__ W2, const float* __restrict__ dinv,
        uint4* __restrict__ hs2h, int n) {
    __shared__ float acc[BW * 9];
    __shared__ float sW[NHID * NOUT];
    __shared__ float sb[NHID];
    int b = blockIdx.x, t = threadIdx.x;
    for (int k = t; k < BW * 9; k += 256) acc[k] = 0.f;
    if (t < NHID * NOUT) sW[t] = W2[t];
    if (t < NHID) sb[t] = b1[t];
    __syncthreads();
    int s0 = boff[b], c = bcnt[b];
    for (int j = s0 + t, jend = s0 + c; j < jend; j += 256) {
        unsigned int p = __builtin_nontemporal_load(bucketed + j);
        uint4 u = hB[p >> BSHIFT];
        acc8(acc + (p & (BW - 1)) * 9, u);
    }
    __syncthreads();
    if (t >= BW) return;
    int node = (b << BSHIFT) + t;
    if (node >= n) return;
    float di = dinv[node];
    float z[NHID];
    {
        const float4* ap = (const float4*)(aggA + (size_t)node * 8);
        float4 a0 = ap[0], a1 = ap[1];
        z[0] = fmaxf(a0.x * di + sb[0], 0.f);
        z[1] = fmaxf(a0.y * di + sb[1], 0.f);
        z[2] = fmaxf(a0.z * di + sb[2], 0.f);
        z[3] = fmaxf(a0.w * di + sb[3], 0.f);
        z[4] = fmaxf(a1.x * di + sb[4], 0.f);
        z[5] = fmaxf(a1.y * di + sb[5], 0.f);
        z[6] = fmaxf(a1.z * di + sb[6], 0.f);
        z[7] = fmaxf(a1.w * di + sb[7], 0.f);
    }
    {
        uint4 sv = hB[node];
        unsigned int us[4] = {sv.x, sv.y, sv.z, sv.w};
        float* a = acc + t * 9;
#pragma unroll
        for (int q = 0; q < 4; q++) {
            float2 f = __half22float2(*(const __half2*)&us[q]);
            z[8 + 2 * q] = fmaxf((a[2 * q] + f.x) * di + sb[8 + 2 * q], 0.f);
            z[9 + 2 * q] = fmaxf((a[2 * q + 1] + f.y) * di + sb[9 + 2 * q], 0.f);
        }
    }
    float h[8];
#pragma unroll
    for (int kk = 0; kk < NOUT; kk++) {
        float s = 0.f;
#pragma unroll
        for (int jj = 0; jj < NHID; jj++) s += z[jj] * sW[jj * NOUT + kk];
        h[kk] = s * di;
    }
    h[6] = 0.f; h[7] = 0.f;
    union { __half2 hh[4]; uint4 u; } pk;
#pragma unroll
    for (int q = 0; q < 4; q++) pk.hh[q] = __floats2half2_rn(h[2 * q], h[2 * q + 1]);
    hs2h[node] = pk.u;
}

__device__ __forceinline__ void acc6(float* a, uint4 u) {
    unsigned int us[3] = {u.x, u.y, u.z};
#pragma unroll
    for (int w = 0; w < 3; w++) {
        float2 fv = __half22float2(*(const __half2*)&us[w]);
        atomicAdd(a + 2 * w, fv.x);
        atomicAdd(a + 2 * w + 1, fv.y);
    }
}

// layer2 aggregate + bias + log_softmax (table 3.2MB, L2-resident)
__global__ __launch_bounds__(256, 4) void
k_agg2(const unsigned int* __restrict__ bucketed, const int* __restrict__ boff,
       const int* __restrict__ bcnt, const uint4* __restrict__ hs2h,
       const float* __restrict__ b2, const float* __restrict__ dinv,
       float* __restrict__ out, int n) {
    __shared__ float acc[BW * 7];
    __shared__ float sb[NOUT];
    int b = blockIdx.x, t = threadIdx.x;
    for (int k = t; k < BW * 7; k += 256) acc[k] = 0.f;
    if (t < NOUT) sb[t] = b2[t];
    __syncthreads();
    int s0 = boff[b], c = bcnt[b];
    for (int j = s0 + t, jend = s0 + c; j < jend; j += 256) {
        unsigned int p = __builtin_nontemporal_load(bucketed + j);
        uint4 u = hs2h[p >> BSHIFT];
        acc6(acc + (p & (BW - 1)) * 7, u);
    }
    __syncthreads();
    if (t >= BW) return;
    int node = (b << BSHIFT) + t;
    if (node >= n) return;
    float di = dinv[node];
    uint4 sv = hs2h[node];
    unsigned int us[3] = {sv.x, sv.y, sv.z};
    float v[NOUT];
    float* a = acc + t * 7;
#pragma unroll
    for (int q = 0; q < 3; q++) {
        float2 f = __half22float2(*(const __half2*)&us[q]);
        v[2 * q]     = (a[2 * q] + f.x) * di + sb[2 * q];
        v[2 * q + 1] = (a[2 * q + 1] + f.y) * di + sb[2 * q + 1];
    }
    float m = -1e30f;
#pragma unroll
    for (int k = 0; k < NOUT; k++) m = fmaxf(m, v[k]);
    float se = 0.f;
#pragma unroll
    for (int k = 0; k < NOUT; k++) se += expf(v[k] - m);
    float l = logf(se);
#pragma unroll
    for (int k = 0; k < NOUT; k++) out[(size_t)node * NOUT + k] = v[k] - m - l;
}

extern "C" void kernel_launch(void* const* d_in, const int* in_sizes, int n_in,
                              void* d_out, int out_size, void* d_ws, size_t ws_size,
                              hipStream_t stream) {
    const float* x  = (const float*)d_in[0];
    const int*   ei = (const int*)d_in[1];
    const float* W1 = (const float*)d_in[2];
    const float* b1 = (const float*)d_in[3];
    const float* W2 = (const float*)d_in[4];
    const float* b2 = (const float*)d_in[5];
    float* out = (float*)d_out;

    int n  = in_sizes[0] / NFEAT_IN;   // 200000
    int ne = in_sizes[1] / 2;          // 6400000
    const int* src = ei;
    const int* dst = ei + ne;

    char* base = (char*)d_ws;
    size_t off = 0;
    auto alloc = [&](size_t bytes) {
        void* p = base + off;
        off += (bytes + 63) & ~(size_t)63;
        return p;
    };
    int* bcnt = (int*)alloc(NBMAX * 4);
    int* boff = (int*)alloc(NBMAX * 4);
    int* bcur = (int*)alloc(NBMAX * 4);
    unsigned int* bucketed = (unsigned int*)alloc((size_t)ne * 4);
    float* dinv = (float*)alloc((size_t)n * 4);
    uint4* hA   = (uint4*)alloc((size_t)n * 16);
    uint4* hB   = (uint4*)alloc((size_t)n * 16);
    float* aggA = (float*)alloc((size_t)n * 32);
    uint4* hs2h = (uint4*)alloc((size_t)n * 16);

    int nb = (n + BW - 1) >> BSHIFT;          // 1563
    int gp = (ne + CHUNK - 1) / CHUNK;        // 782
    int gn = (n + 255) / 256;

    k_zero<<<(NBMAX + 255) / 256, 256, 0, stream>>>(bcnt, NBMAX);
    k_hist<<<256, 256, 0, stream>>>(dst, bcnt, ne);
    k_scan<<<1, 1024, 0, stream>>>(bcnt, boff, bcur);
    k_partition<<<gp, PB, 0, stream>>>(src, dst, bcur, bucketed, ne);
    k_bucket_dinv<<<nb, 256, 0, stream>>>(bucketed, boff, bcnt, dinv, n);
    k_dense1<<<gn, 256, 0, stream>>>(x, W1, dinv, hA, hB, n);
    k_agg1a<<<nb, 256, 0, stream>>>(bucketed, boff, bcnt, hA, aggA, n);
    k_agg1b<<<nb, 256, 0, stream>>>(bucketed, boff, bcnt, hB, aggA, b1, W2, dinv, hs2h, n);
    k_agg2<<<nb, 256, 0, stream>>>(bucketed, boff, bcnt, hs2h, b2, dinv, out, n);
}